// Round 1
// 9461.745 us; speedup vs baseline: 2.9624x; 2.9624x over previous
//
#include <hip/hip_runtime.h>

// HyperLSTM + MDN decoder — f32 in, f32 out.
// R7: latency-bound serial-dot kernels replaced by LDS-staged, split-K,
// all-batch-per-block tile GEMMs. Weights read once per step.
#define MM     20
#define LATENT 128
#define IN_DIM 133
#define HD     1024
#define HD4    4096
#define HY     256
#define FF     64
#define NSEQ   128
#define BB     64
#define OUT_DIM 123   // 6*M+3

// Persistent state + per-step intermediates in __device__ globals.
__device__ float g_h   [BB * HD];
__device__ float g_c   [BB * HD];
__device__ float g_hh  [BB * HY];
__device__ float g_ch  [BB * HY];
__device__ float g_hWh0[BB * HD4];   // h[0:512]   @ Wh
__device__ float g_hWh1[BB * HD4];   // h[512:1024]@ Wh
__device__ float g_xWx [BB * HD4];
__device__ float g_gx  [BB * HD];    // x  @ Wxh_hy[:133]  (+ b_hy)
__device__ float g_ghh [BB * HD];    // hh @ Whh_hy
__device__ float g_gh0 [BB * HD];    // h[0:512]   @ Wxh_hy[133:645]
__device__ float g_gh1 [BB * HD];    // h[512:1024]@ Wxh_hy[645:1157]
__device__ float g_z   [BB * 3 * HY];

__device__ __forceinline__ float sigf(float x) { return 1.0f / (1.0f + expf(-x)); }

// ---------------------------------------------------------------------------
// init: s0 = tanh(z @ fc_in_w + fc_in_b) -> h0,c0,hh0,ch0.  grid 64 x 256
// ---------------------------------------------------------------------------
__global__ __launch_bounds__(256) void init_kernel(
    const float* __restrict__ z, const float* __restrict__ fc_in_w,
    const float* __restrict__ fc_in_b)
{
    int b = blockIdx.x, tid = threadIdx.x;
    __shared__ float zs[LATENT];
    if (tid < LATENT) zs[tid] = z[b * LATENT + tid];
    __syncthreads();
    for (int j = tid; j < 2560; j += 256) {
        float acc = fc_in_b[j];
        #pragma unroll 4
        for (int k = 0; k < LATENT; k++) acc += zs[k] * fc_in_w[k * 2560 + j];
        float s = tanhf(acc);
        if      (j < 1024) g_h [b * 1024 + j]          = s;
        else if (j < 2048) g_c [b * 1024 + (j - 1024)] = s;
        else if (j < 2304) g_hh[b * 256  + (j - 2048)] = s;
        else               g_ch[b * 256  + (j - 2304)] = s;
    }
}

// ---------------------------------------------------------------------------
// K1: unified tile GEMM. Block = one work unit: 64 b x 32 cols, one K chunk.
// Unit map (heavy units first so they dispatch first):
//   [0,4)     proj  (k=1024, W=fc_proj_w, epilogue for t-1)
//   [4,260)   hWh   (128 col-tiles x 2 k-chunks of 512)
//   [260,292) g-h0  (k=512)
//   [292,324) g-h1  (k=512)
//   [324,356) g-hh  (k=256)
//   [356,388) g-x   (k=133, + b_hy)
//   [388,516) xWx   (k=133)
// Tail launch (t==NSEQ): grid=4, proj only.
// ---------------------------------------------------------------------------
__global__ __launch_bounds__(512) void k1_kernel(
    const float* __restrict__ strokes, const float* __restrict__ Wx,
    const float* __restrict__ Wh,      const float* __restrict__ Wxh_hy,
    const float* __restrict__ Whh_hy,  const float* __restrict__ b_hy,
    const float* __restrict__ fc_proj_w, const float* __restrict__ fc_proj_b,
    float* __restrict__ out, int t)
{
    __shared__ float Apan[64][68];   // [b][kk], pad 68 -> conflict-free b128
    __shared__ float Wpan[64][32];   // [kk][c]
    int u = blockIdx.x, tid = threadIdx.x;

    const float* Ap; int lda, kl;
    const float* Wp; int ldw, ncols, co;
    const float* bias = nullptr;
    float* Op = nullptr; int ldo = 0;
    bool isProj = false;

    if (u < 4) {
        if (t == 0) return;
        Ap = g_h; lda = HD; kl = HD;
        Wp = fc_proj_w; ldw = OUT_DIM; ncols = OUT_DIM; co = u * 32;
        isProj = true;
    } else if (u < 260) {
        int i = u - 4, chunk = i >> 7, tile = i & 127;
        Ap = g_h + chunk * 512; lda = HD; kl = 512;
        Wp = Wh + chunk * 512 * HD4; ldw = HD4; ncols = HD4; co = tile * 32;
        Op = chunk ? g_hWh1 : g_hWh0; ldo = HD4;
    } else if (u < 292) {
        Ap = g_h; lda = HD; kl = 512;
        Wp = Wxh_hy + 133 * HD; ldw = HD; ncols = HD; co = (u - 260) * 32;
        Op = g_gh0; ldo = HD;
    } else if (u < 324) {
        Ap = g_h + 512; lda = HD; kl = 512;
        Wp = Wxh_hy + 645 * HD; ldw = HD; ncols = HD; co = (u - 292) * 32;
        Op = g_gh1; ldo = HD;
    } else if (u < 356) {
        Ap = g_hh; lda = HY; kl = HY;
        Wp = Whh_hy; ldw = HD; ncols = HD; co = (u - 324) * 32;
        Op = g_ghh; ldo = HD;
    } else if (u < 388) {
        Ap = strokes + t * BB * IN_DIM; lda = IN_DIM; kl = IN_DIM;
        Wp = Wxh_hy; ldw = HD; ncols = HD; co = (u - 356) * 32;
        bias = b_hy; Op = g_gx; ldo = HD;
    } else {
        Ap = strokes + t * BB * IN_DIM; lda = IN_DIM; kl = IN_DIM;
        Wp = Wx; ldw = HD4; ncols = HD4; co = (u - 388) * 32;
        Op = g_xWx; ldo = HD4;
    }

    int c4 = tid & 7, b = tid >> 3;           // compute mapping: 8 c4 x 64 b
    int sb = tid >> 3, skq = tid & 7;         // A-staging: row, kk-octet
    int wkk = tid >> 3, wc4 = tid & 7;        // W-staging: row, col-quad
    bool a_al = (lda & 3) == 0;
    bool w_al = (ldw & 3) == 0;
    float4 acc = {0.f, 0.f, 0.f, 0.f};

    int np = (kl + 63) >> 6;
    for (int p = 0; p < np; p++) {
        int kbase = p << 6;
        __syncthreads();
        {   // stage A panel [64 b][64 kk]
            int kk0 = skq * 8;
            if (a_al && kbase + kk0 + 8 <= kl) {
                const float4* src = (const float4*)(Ap + sb * lda + kbase + kk0);
                *(float4*)&Apan[sb][kk0]     = src[0];
                *(float4*)&Apan[sb][kk0 + 4] = src[1];
            } else {
                for (int i = 0; i < 8; i++) {
                    int ka = kbase + kk0 + i;
                    Apan[sb][kk0 + i] = (ka < kl) ? Ap[sb * lda + ka] : 0.f;
                }
            }
        }
        {   // stage W panel [64 kk][32 c]
            int ka = kbase + wkk;
            if (w_al && ka < kl) {
                *(float4*)&Wpan[wkk][wc4 * 4] =
                    *(const float4*)(Wp + ka * ldw + co + wc4 * 4);
            } else {
                for (int i = 0; i < 4; i++) {
                    int cc = co + wc4 * 4 + i;
                    Wpan[wkk][wc4 * 4 + i] =
                        (ka < kl && cc < ncols) ? Wp[ka * ldw + cc] : 0.f;
                }
            }
        }
        __syncthreads();
        const float4* arow = (const float4*)&Apan[b][0];
        #pragma unroll 4
        for (int k4 = 0; k4 < 16; k4++) {
            float4 a  = arow[k4];
            float4 w0 = *(float4*)&Wpan[k4 * 4 + 0][c4 * 4];
            float4 w1 = *(float4*)&Wpan[k4 * 4 + 1][c4 * 4];
            float4 w2 = *(float4*)&Wpan[k4 * 4 + 2][c4 * 4];
            float4 w3 = *(float4*)&Wpan[k4 * 4 + 3][c4 * 4];
            acc.x += a.x * w0.x + a.y * w1.x + a.z * w2.x + a.w * w3.x;
            acc.y += a.x * w0.y + a.y * w1.y + a.z * w2.y + a.w * w3.y;
            acc.z += a.x * w0.z + a.y * w1.z + a.z * w2.z + a.w * w3.z;
            acc.w += a.x * w0.w + a.y * w1.w + a.z * w2.w + a.w * w3.w;
        }
    }

    if (!isProj) {
        int cc = co + c4 * 4;
        if (bias) {
            acc.x += bias[cc];     acc.y += bias[cc + 1];
            acc.z += bias[cc + 2]; acc.w += bias[cc + 3];
        }
        *(float4*)&Op[b * ldo + cc] = acc;
    } else {
        int tp = t - 1;
        float v[4] = {acc.x, acc.y, acc.z, acc.w};
        int colb = co + c4 * 4;
        if (colb == 120) {               // pen-state softmax (3 logits, 1 thread)
            float p0 = v[0] + fc_proj_b[120];
            float p1 = v[1] + fc_proj_b[121];
            float p2 = v[2] + fc_proj_b[122];
            float mx = fmaxf(p0, fmaxf(p1, p2));
            float e0 = expf(p0 - mx), e1 = expf(p1 - mx), e2 = expf(p2 - mx);
            float s = e0 + e1 + e2;
            int ob = 983040 + tp * (BB * 3) + b * 3;
            out[ob + 0] = e0 / s; out[ob + 1] = e1 / s; out[ob + 2] = e2 / s;
        } else {
            for (int j = 0; j < 4; j++) {
                int col = colb + j;
                if (col >= 120) continue;
                float val = v[j] + fc_proj_b[col];
                int m = col / 6, r = col - m * 6;
                int oidx = tp * (MM * BB) + m * BB + b;
                if      (r == 0) out[oidx]          = 1.0f;   // softmax over size-1 axis
                else if (r == 1) out[163840 + oidx] = val;
                else if (r == 2) out[327680 + oidx] = val;
                else if (r == 3) out[491520 + oidx] = expf(val);
                else if (r == 4) out[655360 + oidx] = expf(val);
                else             out[819200 + oidx] = tanhf(val);
            }
        }
    }
}

// ---------------------------------------------------------------------------
// K2a: hyper-LSTM pointwise update (sum 4 split-K chunks). grid 64 x 256.
// ---------------------------------------------------------------------------
__global__ __launch_bounds__(256) void k2a_kernel()
{
    int b = blockIdx.x, e = threadIdx.x;
    int base = b * HD;
    float gi = g_gx[base + e]       + g_ghh[base + e]
             + g_gh0[base + e]      + g_gh1[base + e];
    float gf = g_gx[base + 256 + e] + g_ghh[base + 256 + e]
             + g_gh0[base + 256 + e]+ g_gh1[base + 256 + e];
    float gg = g_gx[base + 512 + e] + g_ghh[base + 512 + e]
             + g_gh0[base + 512 + e]+ g_gh1[base + 512 + e];
    float go = g_gx[base + 768 + e] + g_ghh[base + 768 + e]
             + g_gh0[base + 768 + e]+ g_gh1[base + 768 + e];
    float ch = g_ch[b * HY + e];
    ch = sigf(gf) * ch + sigf(gi) * tanhf(gg);
    float hh = sigf(go) * tanhf(ch);
    g_ch[b * HY + e] = ch;
    g_hh[b * HY + e] = hh;
}

// ---------------------------------------------------------------------------
// K2b: z = hh @ {Wzx,Wzh,Wzb} (+bias). grid 48 (3 tensors x 16 col-tiles) x 512.
// hh and the 16-col W tile both staged in LDS; all-LDS dot.
// ---------------------------------------------------------------------------
__global__ __launch_bounds__(512) void k2b_kernel(
    const float* __restrict__ Wzx, const float* __restrict__ bzx,
    const float* __restrict__ Wzh, const float* __restrict__ bzh,
    const float* __restrict__ Wzb)
{
    __shared__ float hh_l[64][257];   // pad 257 -> (b+k)%32 banks, conflict-free
    __shared__ float wn[256][16];
    int blk = blockIdx.x, tid = threadIdx.x;
    int ten = blk >> 4, c0 = (blk & 15) * 16;
    const float* Wz = (ten == 0) ? Wzx : (ten == 1) ? Wzh : Wzb;
    {   // stage hh[64][256]
        int b = tid >> 3, s0 = (tid & 7) * 32;
        const float4* src = (const float4*)(g_hh + b * HY + s0);
        #pragma unroll
        for (int i = 0; i < 8; i++) {
            float4 v = src[i];
            hh_l[b][s0 + i * 4 + 0] = v.x;
            hh_l[b][s0 + i * 4 + 1] = v.y;
            hh_l[b][s0 + i * 4 + 2] = v.z;
            hh_l[b][s0 + i * 4 + 3] = v.w;
        }
    }
    {   // stage W tile [256][16]
        int k = tid >> 1, c8 = (tid & 1) * 8;
        const float4* src = (const float4*)(Wz + k * HY + c0 + c8);
        *(float4*)&wn[k][c8]     = src[0];
        *(float4*)&wn[k][c8 + 4] = src[1];
    }
    __syncthreads();
    int c = tid & 15, bb = tid >> 4;    // 16 cols x 32 b-pairs
    float a0 = 0.f, a1 = 0.f;
    #pragma unroll 8
    for (int k = 0; k < HY; k++) {
        float w = wn[k][c];
        a0 += hh_l[bb][k]      * w;
        a1 += hh_l[bb + 32][k] * w;
    }
    float bv = (ten == 0) ? bzx[c0 + c] : (ten == 1) ? bzh[c0 + c] : 0.f;
    g_z[bb * 768        + ten * HY + c0 + c] = a0 + bv;
    g_z[(bb + 32) * 768 + ten * HY + c0 + c] = a1 + bv;
}

// ---------------------------------------------------------------------------
// K3: einsum (z x D) + combine with xWx/hWh/b0 + main LSTM update.
// grid 256 = 8 b-groups(8 b) x 32 hi-slices(32). D read 8x/step (was 64x).
// ---------------------------------------------------------------------------
__global__ __launch_bounds__(512) void k3_kernel(
    const float* __restrict__ Dx, const float* __restrict__ Dh,
    const float* __restrict__ Db, const float* __restrict__ b0w)
{
    __shared__ float z_l[8][768];
    __shared__ float pre_l[8][4][32];
    int blk = blockIdx.x, tid = threadIdx.x;
    int bg = blk >> 5, sl = blk & 31;
    int hi0 = sl * 32;
    {   // stage z for 8 b
        const float4* src = (const float4*)(g_z + bg * 8 * 768);
        float4* dst = (float4*)&z_l[0][0];
        for (int i = tid; i < 1536; i += 512) dst[i] = src[i];
    }
    __syncthreads();
    int hi_l = tid & 31, gg = (tid >> 5) & 3, b4 = tid >> 7;
    int hi = hi0 + hi_l;
    const float* dxp = Dx + gg * 64 * HD + hi;
    const float* dhp = Dh + gg * 64 * HD + hi;
    const float* dbp = Db + gg * 64 * HD + hi;
    const float* zx0 = &z_l[b4][gg * 64];
    const float* zh0 = &z_l[b4][256 + gg * 64];
    const float* zb0 = &z_l[b4][512 + gg * 64];
    const float* zx1 = &z_l[b4 + 4][gg * 64];
    const float* zh1 = &z_l[b4 + 4][256 + gg * 64];
    const float* zb1 = &z_l[b4 + 4][512 + gg * 64];
    float ax0 = 0.f, ah0 = 0.f, ab0 = 0.f, ax1 = 0.f, ah1 = 0.f, ab1 = 0.f;
    #pragma unroll 4
    for (int f = 0; f < FF; f++) {
        float dx = dxp[f * HD], dh = dhp[f * HD], db = dbp[f * HD];
        ax0 += zx0[f] * dx; ah0 += zh0[f] * dh; ab0 += zb0[f] * db;
        ax1 += zx1[f] * dx; ah1 += zh1[f] * dh; ab1 += zb1[f] * db;
    }
    int idx = gg * HD + hi;
    int b0i = bg * 8 + b4, b1i = b0i + 4;
    float pre0 = ax0 * g_xWx[b0i * HD4 + idx]
               + ah0 * (g_hWh0[b0i * HD4 + idx] + g_hWh1[b0i * HD4 + idx])
               + ab0 + b0w[idx];
    float pre1 = ax1 * g_xWx[b1i * HD4 + idx]
               + ah1 * (g_hWh0[b1i * HD4 + idx] + g_hWh1[b1i * HD4 + idx])
               + ab1 + b0w[idx];
    pre_l[b4][gg][hi_l]     = pre0;
    pre_l[b4 + 4][gg][hi_l] = pre1;
    __syncthreads();
    if (tid < 256) {
        int bi = tid >> 5, hl = tid & 31;
        int b = bg * 8 + bi, ha = b * HD + hi0 + hl;
        float pi = pre_l[bi][0][hl], pf = pre_l[bi][1][hl];
        float pg = pre_l[bi][2][hl], po = pre_l[bi][3][hl];
        float cv = g_c[ha];
        float nc = sigf(pf) * cv + sigf(pi) * tanhf(pg);
        float nh = sigf(po) * tanhf(nc);
        g_c[ha] = nc;
        g_h[ha] = nh;
    }
}

// ---------------------------------------------------------------------------
extern "C" void kernel_launch(void* const* d_in, const int* in_sizes, int n_in,
                              void* d_out, int out_size, void* d_ws, size_t ws_size,
                              hipStream_t stream)
{
    const float* z         = (const float*)d_in[0];
    const float* strokes   = (const float*)d_in[1];
    const float* fc_in_w   = (const float*)d_in[2];
    const float* fc_in_b   = (const float*)d_in[3];
    const float* fc_proj_w = (const float*)d_in[4];
    const float* fc_proj_b = (const float*)d_in[5];
    const float* Wx        = (const float*)d_in[6];
    const float* Wh        = (const float*)d_in[7];
    const float* b0w       = (const float*)d_in[8];
    const float* Wxh_hy    = (const float*)d_in[9];
    const float* Whh_hy    = (const float*)d_in[10];
    const float* b_hy      = (const float*)d_in[11];
    const float* Wzx       = (const float*)d_in[12];
    const float* bzx       = (const float*)d_in[13];
    const float* Wzh       = (const float*)d_in[14];
    const float* bzh       = (const float*)d_in[15];
    const float* Wzb       = (const float*)d_in[16];
    const float* Dx        = (const float*)d_in[17];
    const float* Dh        = (const float*)d_in[18];
    const float* Db        = (const float*)d_in[19];
    (void)d_ws; (void)ws_size;
    float* out = (float*)d_out;

    init_kernel<<<64, 256, 0, stream>>>(z, fc_in_w, fc_in_b);
    for (int t = 0; t < NSEQ; t++) {
        k1_kernel<<<516, 512, 0, stream>>>(strokes, Wx, Wh, Wxh_hy, Whh_hy,
                                           b_hy, fc_proj_w, fc_proj_b, out, t);
        k2a_kernel<<<64, 256, 0, stream>>>();
        k2b_kernel<<<48, 512, 0, stream>>>(Wzx, bzx, Wzh, bzh, Wzb);
        k3_kernel<<<256, 512, 0, stream>>>(Dx, Dh, Db, b0w);
    }
    // tail: projection + MDN for t = 127 (proj units are blocks 0..3)
    k1_kernel<<<4, 512, 0, stream>>>(strokes, Wx, Wh, Wxh_hy, Whh_hy,
                                     b_hy, fc_proj_w, fc_proj_b, out, NSEQ);
}

// Round 2
// 8251.456 us; speedup vs baseline: 3.3970x; 1.1467x over previous
//
#include <hip/hip_runtime.h>

// HyperLSTM + MDN decoder — f32 in, f32 out.
// R8: K1 rewritten as 4x4 register-blocked 64x128-tile GEMM, double-buffered
// LDS, W staged via global_load_lds_dwordx4 (issue-early), uniform 256-k
// split-K units (212 blocks, 1/CU). Proj split-K with epilogue moved to K2a.
#define MM     20
#define LATENT 128
#define IN_DIM 133
#define HD     1024
#define HD4    4096
#define HY     256
#define FF     64
#define NSEQ   128
#define BB     64
#define OUT_DIM 123   // 6*M+3
#define NU     212    // K1 unit count

// Persistent state + per-step intermediates in __device__ globals.
__device__ float g_h   [BB * HD];
__device__ float g_c   [BB * HD];
__device__ float g_hh  [BB * HY];
__device__ float g_ch  [BB * HY];
__device__ float g_hWh [4][BB * HD4];  // h@Wh, 4 k-chunks of 256
__device__ float g_xWx [BB * HD4];
__device__ float g_gH  [4][BB * HD];   // h-part of hyper gates, 4 k-chunks
__device__ float g_ghh [BB * HD];      // hh @ Whh_hy
__device__ float g_gx  [BB * HD];      // x  @ Wxh_hy[:133] (+ b_hy)
__device__ float g_z   [BB * 3 * HY];
__device__ float g_proj[4][BB * 128];  // proj split-K partials

__device__ __forceinline__ float sigf(float x) { return 1.0f / (1.0f + expf(-x)); }

__device__ __forceinline__ void gload_lds16(const float* g, float* l) {
    __builtin_amdgcn_global_load_lds(
        (const __attribute__((address_space(1))) void*)g,
        (__attribute__((address_space(3))) void*)l, 16, 0, 0);
}

// ---------------------------------------------------------------------------
// init: s0 = tanh(z @ fc_in_w + fc_in_b) -> h0,c0,hh0,ch0.  grid 64 x 256
// ---------------------------------------------------------------------------
__global__ __launch_bounds__(256) void init_kernel(
    const float* __restrict__ z, const float* __restrict__ fc_in_w,
    const float* __restrict__ fc_in_b)
{
    int b = blockIdx.x, tid = threadIdx.x;
    __shared__ float zs[LATENT];
    if (tid < LATENT) zs[tid] = z[b * LATENT + tid];
    __syncthreads();
    for (int j = tid; j < 2560; j += 256) {
        float acc = fc_in_b[j];
        #pragma unroll 4
        for (int k = 0; k < LATENT; k++) acc += zs[k] * fc_in_w[k * 2560 + j];
        float s = tanhf(acc);
        if      (j < 1024) g_h [b * 1024 + j]          = s;
        else if (j < 2048) g_c [b * 1024 + (j - 1024)] = s;
        else if (j < 2304) g_hh[b * 256  + (j - 2048)] = s;
        else               g_ch[b * 256  + (j - 2304)] = s;
    }
}

// ---------------------------------------------------------------------------
// K1: uniform tile GEMM, 64 b x 128 cols per block, k-chunk <= 256.
// Thread: 4 rows x 4 cols (16 outputs). LDS double-buffered.
// Unit map:
//   [0,4)     proj  4 k-chunks of 256 -> g_proj[chunk]   (epilogue in K2a)
//   [4,132)   hWh   32 ctiles x 4 k-chunks -> g_hWh[chunk]
//   [132,164) xWx   32 ctiles, k=133
//   [164,196) g-h   8 ctiles x 4 k-chunks -> g_gH[chunk]
//   [196,204) g-hh  8 ctiles, k=256
//   [204,212) g-x   8 ctiles, k=133, +b_hy
// Tail launch (t==NSEQ): grid=4 (proj only).
// ---------------------------------------------------------------------------
__global__ __launch_bounds__(512) void k1_kernel(
    const float* __restrict__ strokes, const float* __restrict__ Wx,
    const float* __restrict__ Wh,      const float* __restrict__ Wxh_hy,
    const float* __restrict__ Whh_hy,  const float* __restrict__ b_hy,
    const float* __restrict__ fc_proj_w, int t)
{
    __shared__ float At[2][64][68];     // transposed A panel [k][b], pad 68
    __shared__ float Wt[2][64 * 128];   // W panel [k][c], linear for gload_lds

    int u = blockIdx.x, tid = threadIdx.x;

    const float* Ap; int lda, kl; bool aS = false;
    const float* Wp; int ldw, co;  bool wS = false; int ncols = 0;
    const float* bias = nullptr;
    float* Op; int ldo;

    if (u < 4) {                               // proj (for step t-1)
        if (t == 0) return;
        Ap = g_h + u * 256; lda = HD; kl = 256;
        Wp = fc_proj_w + u * 256 * OUT_DIM; ldw = OUT_DIM; co = 0;
        wS = true; ncols = OUT_DIM;
        Op = g_proj[u]; ldo = 128;
    } else if (u < 132) {                      // h @ Wh
        int i = u - 4, ct = i & 31, ch = i >> 5;
        Ap = g_h + ch * 256; lda = HD; kl = 256;
        Wp = Wh + ch * 256 * HD4; ldw = HD4; co = ct * 128;
        Op = g_hWh[ch]; ldo = HD4;
    } else if (u < 164) {                      // x @ Wx
        int ct = u - 132;
        Ap = strokes + t * BB * IN_DIM; lda = IN_DIM; kl = IN_DIM; aS = true;
        Wp = Wx; ldw = HD4; co = ct * 128;
        Op = g_xWx; ldo = HD4;
    } else if (u < 196) {                      // h part of hyper gates
        int i = u - 164, ct = i & 7, ch = i >> 3;
        Ap = g_h + ch * 256; lda = HD; kl = 256;
        Wp = Wxh_hy + (133 + ch * 256) * HD; ldw = HD; co = ct * 128;
        Op = g_gH[ch]; ldo = HD;
    } else if (u < 204) {                      // hh @ Whh_hy
        int ct = u - 196;
        Ap = g_hh; lda = HY; kl = HY;
        Wp = Whh_hy; ldw = HD; co = ct * 128;
        Op = g_ghh; ldo = HD;
    } else {                                   // x part of hyper gates (+b_hy)
        int ct = u - 204;
        Ap = strokes + t * BB * IN_DIM; lda = IN_DIM; kl = IN_DIM; aS = true;
        Wp = Wxh_hy; ldw = HD; co = ct * 128;
        bias = b_hy; Op = g_gx; ldo = HD;
    }

    int arow = tid >> 3, aoct = (tid & 7) << 3;     // A staging map
    int lane = tid & 63, wv = tid >> 6;             // W staging map
    int colb = lane & 31, rsub = lane >> 5;
    int cg = tid & 31, bg = tid >> 5;               // compute map

    float ar[8];
    int np = (kl + 63) >> 6;
    const float* apr = Ap + arow * lda;

    // ---- stage panel 0
    if (!wS) {
        #pragma unroll
        for (int q = 0; q < 4; q++) {
            int chunk = (wv << 2) + q;
            int kr = (chunk << 1) + rsub; if (kr > kl - 1) kr = kl - 1;
            gload_lds16(Wp + kr * ldw + co + (colb << 2), &Wt[0][chunk << 8]);
        }
    } else {
        #pragma unroll
        for (int q = 0; q < 16; q++) {
            int i2 = (q << 9) + tid, r = i2 >> 7, c = i2 & 127;
            Wt[0][i2] = (c < ncols) ? Wp[r * ldw + c] : 0.f;
        }
    }
    if (!aS) {
        float4 v0 = *(const float4*)(apr + aoct);
        float4 v1 = *(const float4*)(apr + aoct + 4);
        ar[0]=v0.x; ar[1]=v0.y; ar[2]=v0.z; ar[3]=v0.w;
        ar[4]=v1.x; ar[5]=v1.y; ar[6]=v1.z; ar[7]=v1.w;
    } else {
        #pragma unroll
        for (int j = 0; j < 8; j++) { int ka = aoct + j; ar[j] = (ka < kl) ? apr[ka] : 0.f; }
    }
    #pragma unroll
    for (int j = 0; j < 8; j++) At[0][aoct + j][arow] = ar[j];
    __syncthreads();

    float4 acc0 = {0,0,0,0}, acc1 = {0,0,0,0}, acc2 = {0,0,0,0}, acc3 = {0,0,0,0};

    for (int p = 0; p < np; p++) {
        int cur = p & 1, nxt = cur ^ 1;
        int kb = (p + 1) << 6;
        bool pref = (p + 1 < np);
        if (pref) {                 // issue-early: W loads land under compute
            if (!wS) {
                #pragma unroll
                for (int q = 0; q < 4; q++) {
                    int chunk = (wv << 2) + q;
                    int kr = kb + (chunk << 1) + rsub; if (kr > kl - 1) kr = kl - 1;
                    gload_lds16(Wp + kr * ldw + co + (colb << 2), &Wt[nxt][chunk << 8]);
                }
            } else {
                #pragma unroll
                for (int q = 0; q < 16; q++) {
                    int i2 = (q << 9) + tid, r = i2 >> 7, c = i2 & 127;
                    int kr = kb + r; if (kr > kl - 1) kr = kl - 1;
                    Wt[nxt][i2] = (c < ncols) ? Wp[kr * ldw + c] : 0.f;
                }
            }
            if (!aS) {
                float4 v0 = *(const float4*)(apr + kb + aoct);
                float4 v1 = *(const float4*)(apr + kb + aoct + 4);
                ar[0]=v0.x; ar[1]=v0.y; ar[2]=v0.z; ar[3]=v0.w;
                ar[4]=v1.x; ar[5]=v1.y; ar[6]=v1.z; ar[7]=v1.w;
            } else {
                #pragma unroll
                for (int j = 0; j < 8; j++) {
                    int ka = kb + aoct + j;
                    ar[j] = (ka < kl) ? apr[ka] : 0.f;
                }
            }
        }
        const float* Ac = &At[cur][0][0];
        const float* Wc = &Wt[cur][0];
        #pragma unroll 8
        for (int k = 0; k < 64; k++) {
            float4 av  = *(const float4*)(Ac + k * 68 + (bg << 2));
            float4 wv4 = *(const float4*)(Wc + (k << 7) + (cg << 2));
            acc0.x += av.x * wv4.x; acc0.y += av.x * wv4.y;
            acc0.z += av.x * wv4.z; acc0.w += av.x * wv4.w;
            acc1.x += av.y * wv4.x; acc1.y += av.y * wv4.y;
            acc1.z += av.y * wv4.z; acc1.w += av.y * wv4.w;
            acc2.x += av.z * wv4.x; acc2.y += av.z * wv4.y;
            acc2.z += av.z * wv4.z; acc2.w += av.z * wv4.w;
            acc3.x += av.w * wv4.x; acc3.y += av.w * wv4.y;
            acc3.z += av.w * wv4.z; acc3.w += av.w * wv4.w;
        }
        if (pref) {
            #pragma unroll
            for (int j = 0; j < 8; j++) At[nxt][aoct + j][arow] = ar[j];
        }
        __syncthreads();
    }

    int cc = co + (cg << 2);
    if (bias) {
        float4 bv = *(const float4*)(bias + cc);
        acc0.x += bv.x; acc0.y += bv.y; acc0.z += bv.z; acc0.w += bv.w;
        acc1.x += bv.x; acc1.y += bv.y; acc1.z += bv.z; acc1.w += bv.w;
        acc2.x += bv.x; acc2.y += bv.y; acc2.z += bv.z; acc2.w += bv.w;
        acc3.x += bv.x; acc3.y += bv.y; acc3.z += bv.z; acc3.w += bv.w;
    }
    float* op = Op + (bg << 2) * ldo + cc;
    *(float4*)(op)           = acc0;
    *(float4*)(op + ldo)     = acc1;
    *(float4*)(op + 2 * ldo) = acc2;
    *(float4*)(op + 3 * ldo) = acc3;
}

// ---------------------------------------------------------------------------
// K2a: blocks [0,64): hyper-LSTM gate-sum + (hh,ch) update (1 b per block).
//      blocks 64,65: proj epilogue + MDN for step t-1 (32 b per block).
// grid 66 x 256.
// ---------------------------------------------------------------------------
__global__ __launch_bounds__(256) void k2a_kernel(
    const float* __restrict__ fc_proj_b, float* __restrict__ out, int t)
{
    int blk = blockIdx.x, tid = threadIdx.x;
    if (blk < 64) {
        if (t >= NSEQ) return;          // tail launch: gates not needed
        int b = blk, base = b * HD;
        float g4[4];
        #pragma unroll
        for (int s = 0; s < 4; s++) {
            int j = base + (s << 8) + tid;
            g4[s] = g_gx[j] + g_ghh[j]
                  + g_gH[0][j] + g_gH[1][j] + g_gH[2][j] + g_gH[3][j];
        }
        float ch = g_ch[b * HY + tid];
        ch = sigf(g4[1]) * ch + sigf(g4[0]) * tanhf(g4[2]);
        float hh = sigf(g4[3]) * tanhf(ch);
        g_ch[b * HY + tid] = ch;
        g_hh[b * HY + tid] = hh;
    } else {
        if (t == 0) return;
        int tp = t - 1;
        int b = ((blk - 64) << 5) + (tid >> 3);
        int cq = tid & 7;
        int base = b << 7;
        int c0 = cq << 4;
        for (int c = c0; c < c0 + 16 && c < 120; c++) {
            float v = g_proj[0][base + c] + g_proj[1][base + c]
                    + g_proj[2][base + c] + g_proj[3][base + c] + fc_proj_b[c];
            int m = c / 6, r = c - m * 6;
            int oidx = tp * (MM * BB) + m * BB + b;
            if      (r == 0) out[oidx]          = 1.0f;  // softmax over size-1 axis
            else if (r == 1) out[163840 + oidx] = v;
            else if (r == 2) out[327680 + oidx] = v;
            else if (r == 3) out[491520 + oidx] = expf(v);
            else if (r == 4) out[655360 + oidx] = expf(v);
            else             out[819200 + oidx] = tanhf(v);
        }
        if (cq == 7) {                  // pen-state softmax (cols 120..122)
            float p0 = g_proj[0][base+120] + g_proj[1][base+120]
                     + g_proj[2][base+120] + g_proj[3][base+120] + fc_proj_b[120];
            float p1 = g_proj[0][base+121] + g_proj[1][base+121]
                     + g_proj[2][base+121] + g_proj[3][base+121] + fc_proj_b[121];
            float p2 = g_proj[0][base+122] + g_proj[1][base+122]
                     + g_proj[2][base+122] + g_proj[3][base+122] + fc_proj_b[122];
            float mx = fmaxf(p0, fmaxf(p1, p2));
            float e0 = expf(p0 - mx), e1 = expf(p1 - mx), e2 = expf(p2 - mx);
            float s = e0 + e1 + e2;
            int ob = 983040 + tp * (BB * 3) + b * 3;
            out[ob + 0] = e0 / s; out[ob + 1] = e1 / s; out[ob + 2] = e2 / s;
        }
    }
}

// ---------------------------------------------------------------------------
// K2b: z = hh @ {Wzx,Wzh,Wzb} (+bias). grid 48 (3 tensors x 16 col-tiles) x 512.
// ---------------------------------------------------------------------------
__global__ __launch_bounds__(512) void k2b_kernel(
    const float* __restrict__ Wzx, const float* __restrict__ bzx,
    const float* __restrict__ Wzh, const float* __restrict__ bzh,
    const float* __restrict__ Wzb)
{
    __shared__ float hh_l[64][257];
    __shared__ float wn[256][16];
    int blk = blockIdx.x, tid = threadIdx.x;
    int ten = blk >> 4, c0 = (blk & 15) * 16;
    const float* Wz = (ten == 0) ? Wzx : (ten == 1) ? Wzh : Wzb;
    {
        int b = tid >> 3, s0 = (tid & 7) * 32;
        const float4* src = (const float4*)(g_hh + b * HY + s0);
        #pragma unroll
        for (int i = 0; i < 8; i++) {
            float4 v = src[i];
            hh_l[b][s0 + i * 4 + 0] = v.x;
            hh_l[b][s0 + i * 4 + 1] = v.y;
            hh_l[b][s0 + i * 4 + 2] = v.z;
            hh_l[b][s0 + i * 4 + 3] = v.w;
        }
    }
    {
        int k = tid >> 1, c8 = (tid & 1) * 8;
        const float4* src = (const float4*)(Wz + k * HY + c0 + c8);
        *(float4*)&wn[k][c8]     = src[0];
        *(float4*)&wn[k][c8 + 4] = src[1];
    }
    __syncthreads();
    int c = tid & 15, bb = tid >> 4;
    float a0 = 0.f, a1 = 0.f;
    #pragma unroll 8
    for (int k = 0; k < HY; k++) {
        float w = wn[k][c];
        a0 += hh_l[bb][k]      * w;
        a1 += hh_l[bb + 32][k] * w;
    }
    float bv = (ten == 0) ? bzx[c0 + c] : (ten == 1) ? bzh[c0 + c] : 0.f;
    g_z[bb * 768        + ten * HY + c0 + c] = a0 + bv;
    g_z[(bb + 32) * 768 + ten * HY + c0 + c] = a1 + bv;
}

// ---------------------------------------------------------------------------
// K3: einsum (z x D) + combine with xWx/hWh/b0 + main LSTM update.
// grid 256 = 8 b-groups(8 b) x 32 hi-slices(32).
// ---------------------------------------------------------------------------
__global__ __launch_bounds__(512) void k3_kernel(
    const float* __restrict__ Dx, const float* __restrict__ Dh,
    const float* __restrict__ Db, const float* __restrict__ b0w)
{
    __shared__ float z_l[8][768];
    __shared__ float pre_l[8][4][32];
    int blk = blockIdx.x, tid = threadIdx.x;
    int bg = blk >> 5, sl = blk & 31;
    int hi0 = sl * 32;
    {
        const float4* src = (const float4*)(g_z + bg * 8 * 768);
        float4* dst = (float4*)&z_l[0][0];
        for (int i = tid; i < 1536; i += 512) dst[i] = src[i];
    }
    __syncthreads();
    int hi_l = tid & 31, gg = (tid >> 5) & 3, b4 = tid >> 7;
    int hi = hi0 + hi_l;
    const float* dxp = Dx + gg * 64 * HD + hi;
    const float* dhp = Dh + gg * 64 * HD + hi;
    const float* dbp = Db + gg * 64 * HD + hi;
    const float* zx0 = &z_l[b4][gg * 64];
    const float* zh0 = &z_l[b4][256 + gg * 64];
    const float* zb0 = &z_l[b4][512 + gg * 64];
    const float* zx1 = &z_l[b4 + 4][gg * 64];
    const float* zh1 = &z_l[b4 + 4][256 + gg * 64];
    const float* zb1 = &z_l[b4 + 4][512 + gg * 64];
    float ax0 = 0.f, ah0 = 0.f, ab0 = 0.f, ax1 = 0.f, ah1 = 0.f, ab1 = 0.f;
    #pragma unroll 4
    for (int f = 0; f < FF; f++) {
        float dx = dxp[f * HD], dh = dhp[f * HD], db = dbp[f * HD];
        ax0 += zx0[f] * dx; ah0 += zh0[f] * dh; ab0 += zb0[f] * db;
        ax1 += zx1[f] * dx; ah1 += zh1[f] * dh; ab1 += zb1[f] * db;
    }
    int idx = gg * HD + hi;
    int b0i = bg * 8 + b4, b1i = b0i + 4;
    float hw0 = g_hWh[0][b0i * HD4 + idx] + g_hWh[1][b0i * HD4 + idx]
              + g_hWh[2][b0i * HD4 + idx] + g_hWh[3][b0i * HD4 + idx];
    float hw1 = g_hWh[0][b1i * HD4 + idx] + g_hWh[1][b1i * HD4 + idx]
              + g_hWh[2][b1i * HD4 + idx] + g_hWh[3][b1i * HD4 + idx];
    float pre0 = ax0 * g_xWx[b0i * HD4 + idx] + ah0 * hw0 + ab0 + b0w[idx];
    float pre1 = ax1 * g_xWx[b1i * HD4 + idx] + ah1 * hw1 + ab1 + b0w[idx];
    pre_l[b4][gg][hi_l]     = pre0;
    pre_l[b4 + 4][gg][hi_l] = pre1;
    __syncthreads();
    if (tid < 256) {
        int bi = tid >> 5, hl = tid & 31;
        int b = bg * 8 + bi, ha = b * HD + hi0 + hl;
        float pi = pre_l[bi][0][hl], pf = pre_l[bi][1][hl];
        float pg = pre_l[bi][2][hl], po = pre_l[bi][3][hl];
        float cv = g_c[ha];
        float nc = sigf(pf) * cv + sigf(pi) * tanhf(pg);
        float nh = sigf(po) * tanhf(nc);
        g_c[ha] = nc;
        g_h[ha] = nh;
    }
}

// ---------------------------------------------------------------------------
extern "C" void kernel_launch(void* const* d_in, const int* in_sizes, int n_in,
                              void* d_out, int out_size, void* d_ws, size_t ws_size,
                              hipStream_t stream)
{
    const float* z         = (const float*)d_in[0];
    const float* strokes   = (const float*)d_in[1];
    const float* fc_in_w   = (const float*)d_in[2];
    const float* fc_in_b   = (const float*)d_in[3];
    const float* fc_proj_w = (const float*)d_in[4];
    const float* fc_proj_b = (const float*)d_in[5];
    const float* Wx        = (const float*)d_in[6];
    const float* Wh        = (const float*)d_in[7];
    const float* b0w       = (const float*)d_in[8];
    const float* Wxh_hy    = (const float*)d_in[9];
    const float* Whh_hy    = (const float*)d_in[10];
    const float* b_hy      = (const float*)d_in[11];
    const float* Wzx       = (const float*)d_in[12];
    const float* bzx       = (const float*)d_in[13];
    const float* Wzh       = (const float*)d_in[14];
    const float* bzh       = (const float*)d_in[15];
    const float* Wzb       = (const float*)d_in[16];
    const float* Dx        = (const float*)d_in[17];
    const float* Dh        = (const float*)d_in[18];
    const float* Db        = (const float*)d_in[19];
    (void)d_ws; (void)ws_size;
    float* out = (float*)d_out;

    init_kernel<<<64, 256, 0, stream>>>(z, fc_in_w, fc_in_b);
    for (int t = 0; t < NSEQ; t++) {
        k1_kernel<<<NU, 512, 0, stream>>>(strokes, Wx, Wh, Wxh_hy, Whh_hy,
                                          b_hy, fc_proj_w, t);
        k2a_kernel<<<66, 256, 0, stream>>>(fc_proj_b, out, t);
        k2b_kernel<<<48, 512, 0, stream>>>(Wzx, bzx, Wzh, bzh, Wzb);
        k3_kernel<<<256, 512, 0, stream>>>(Dx, Dh, Db, b0w);
    }
    // tail: proj + MDN for t = 127
    k1_kernel<<<4, 512, 0, stream>>>(strokes, Wx, Wh, Wxh_hy, Whh_hy,
                                     b_hy, fc_proj_w, NSEQ);
    k2a_kernel<<<66, 256, 0, stream>>>(fc_proj_b, out, NSEQ);
}